// Round 6
// baseline (94.103 us; speedup 1.0000x reference)
//
#include <hip/hip_runtime.h>
#include <hip/hip_fp16.h>

// ---------------------------------------------------------------------------
// ROUND 13: take the gate table OFF the LDS pipe + b128 exchange.
// R12 model (per CU/layer): DS = 48 bperm x5.8 + 24 b64 x8 + 12 gt-b128 x12
// ~= 4.9k cyc -> 39k total; VALU ~20k; barriers ~10k; ~zero overlap at
// 2 waves/SIMD -> 69k cyc ~= 29 us ✓ measured. The gt reads (24% of DS) are
// wave-uniform -> move the table to GLOBAL d_ws (R0/R8-verified pattern:
// scalar/VMEM loads, LDS pipe untouched), pre-splatted to half2 in a coeff
// pre-kernel (also kills ~100 cvt/splat VALU insts/thread/layer). Exchange
// packed as 2x int4 (b128, stride 48 B = minimal 8-dw/bank layout).
// All state math byte-identical to verified R12 (same h2 rounding, same
// signs). Structure (R10-12 verified):
//   out = a^T G a + hb, a=(c0c1,c0s1,s0c1,s0s1); G real sym 4x4 from
//   C = U[:,{0,1024,2048,3072}]. 4 blocks x 512 thr, 8 complex/thread fp16.
//   Flat y = [thread T(9b) | reg r(3b)]; wire w <-> flat bit 11-w:
//     wires 0..2 -> thread bits 8..6: LDS exchange (dbuf, 1 barrier/gate)
//     wires 3..8 -> thread bits 5..0: ds_bpermute (sender pre-combined u,v)
//     wires 9..11 -> reg bits 2..0:  packed in-register (R7 forms)
//   Deferred CNOT: p = ginv9(p); Minv[pb] ^= Minv[pb-1]; physical reg part =
//   cond swap r^4 on c=parity(p_old) + gray3 relabel (rot16 cycles).
// Rot(phi,th,om) = [[(A,-B),(-C,-D)],[(C,-D),(A,B)]], A=ca*ch B=sa*ch
// C=cb*sh D=sb*sh.
// ---------------------------------------------------------------------------

typedef __half2 h2;
struct GateRecH2 { h2 a2, b2, c2, d2; };               // 16 B, splatted

__device__ __forceinline__ float bpermf(int addr4, float v) {
    return __int_as_float(__builtin_amdgcn_ds_bpermute(addr4, __float_as_int(v)));
}
__device__ __forceinline__ h2 bperm2(int addr4, h2 v) {
    int x = __builtin_amdgcn_ds_bpermute(addr4, __builtin_bit_cast(int, v));
    return __builtin_bit_cast(h2, x);
}
__device__ __forceinline__ int ginv9(int y) {          // inverse 9-bit gray
    y ^= y >> 1; y ^= y >> 2; y ^= y >> 4; y ^= y >> 8;
    return y & 511;
}
__device__ __forceinline__ h2 sp(float x) {            // splat f32 -> half2
    return __half2half2(__float2half(x));
}
__device__ __forceinline__ h2 rot16(h2 v) {            // swap the two halves
    unsigned u = __builtin_bit_cast(unsigned, v);
    u = (u << 16) | (u >> 16);
    return __builtin_bit_cast(h2, u);
}
__device__ __forceinline__ h2 bch2(int x)  { return __builtin_bit_cast(h2, x); }
__device__ __forceinline__ int bci(h2 x)   { return __builtin_bit_cast(int, x); }
#define NEGMASK 0x80008000

// R7-verified packed 2x2 gate on an aligned half2 pair.
struct H2C { h2 a, b, c, d, nb, nc, nd; };
__device__ __forceinline__ void reg_pair(h2& a0r, h2& a0i, h2& a1r, h2& a1i,
                                         const H2C& R) {
    const h2 x0r = a0r, x0i = a0i, x1r = a1r, x1i = a1i;
    a0r = __hfma2(R.d,  x1i, __hfma2(R.nc, x1r, __hfma2(R.b,  x0i, __hmul2(R.a, x0r))));
    a0i = __hfma2(R.nd, x1r, __hfma2(R.nc, x1i, __hfma2(R.nb, x0r, __hmul2(R.a, x0i))));
    a1r = __hfma2(R.nb, x1i, __hfma2(R.a,  x1r, __hfma2(R.d,  x0i, __hmul2(R.c, x0r))));
    a1i = __hfma2(R.b,  x1r, __hfma2(R.a,  x1i, __hfma2(R.nd, x0r, __hmul2(R.c, x0i))));
}

// ---- kernel 0: gate tables in d_ws (batch-shared, pre-splatted h2) --------
__global__ void coeff_kernel(const float* __restrict__ wts,
                             GateRecH2* __restrict__ tbl,   // 96 recs
                             h2* __restrict__ w11) {        // 8 x {cP,cQ,cR,cS}
    const int g = threadIdx.x;
    if (g >= 96) return;
    const int l = g / 12, w = g % 12;
    const float* lw = wts + l*36 + w*3;
    const float phi = lw[0], th = lw[1], om = lw[2];
    float ch, sh, ca, sa, cb, sb;
    __sincosf(0.5f*th,       &sh, &ch);
    __sincosf(0.5f*(phi+om), &sa, &ca);
    __sincosf(0.5f*(phi-om), &sb, &cb);
    const float A = ca*ch, B = sa*ch, C = cb*sh, D = sb*sh;
    GateRecH2 r; r.a2 = sp(A); r.b2 = sp(B); r.c2 = sp(C); r.d2 = sp(D);
    tbl[g] = r;
    if (w == 11) {                                     // R12-verified constants
        w11[l*4 + 0] = __halves2half2(__float2half( A), __float2half( C)); // cP
        w11[l*4 + 1] = __halves2half2(__float2half( B), __float2half( D)); // cQ
        w11[l*4 + 2] = __halves2half2(__float2half(-C), __float2half( A)); // cR
        w11[l*4 + 3] = __halves2half2(__float2half( D), __float2half(-B)); // cS
    }
}

// ---- kernel 1: 4 blocks x 512 threads, one column sim per block -----------
__global__ __launch_bounds__(512, 1)
void sim_kernel(const GateRecH2* __restrict__ tbl,
                const h2* __restrict__ w11,
                float2* __restrict__ cols) {
    const int t = threadIdx.x;                      // physical thread (9 bits)
    const int b = blockIdx.x;                       // column 0..3

    __shared__ int4 xb[2][512 * 3];                 // 2 x 24,576 B dbuf
                                                    // (stride 48 B: minimal
                                                    //  8-dw/bank for b128)
    h2 ar2[4], ai2[4];
    const h2 zero = sp(0.f);
#pragma unroll
    for (int k = 0; k < 4; ++k) { ar2[k] = zero; ai2[k] = zero; }
    // basis flat index b<<10 -> T = b<<7, r = 0
    if (t == (b << 7)) ar2[0] = __halves2half2(__float2half(1.f), __float2half(0.f));

    int p = t;                                      // logical thread index
    int Minv[9] = {1, 2, 4, 8, 16, 32, 64, 128, 256};

#pragma unroll 1
    for (int l = 0; l < 8; ++l) {
        const int base = l * 12;
        // ---- wires 0..2: thread bits 8..6, cross-wave via dbuf LDS ----
#pragma unroll
        for (int w = 0; w < 3; ++w) {
            const int4 rv = *reinterpret_cast<const int4*>(tbl + base + w);
            const int pb = 8 - w;
            const bool bs = (p >> pb) & 1;
            const h2 A2    = bch2(rv.x);
            const int bi   = bs ? rv.y : (rv.y ^ NEGMASK);
            const h2 csi2  = bch2(bi);
            const h2 ncsi2 = bch2(bi ^ NEGMASK);
            const h2 cor2  = bch2(bs ? rv.z : (rv.z ^ NEGMASK));
            const h2 D2    = bch2(rv.w);
            const h2 nD2   = bch2(rv.w ^ NEGMASK);
            int4* buf = xb[(l*3 + w) & 1];
            // sender pre-combine (R12 signs): u = cor*xr - D*xi, v = cor*xi + D*xr
            h2 u[4], v[4];
#pragma unroll
            for (int k = 0; k < 4; ++k) {
                u[k] = __hfma2(nD2, ai2[k], __hmul2(cor2, ar2[k]));
                v[k] = __hfma2(D2,  ar2[k], __hmul2(cor2, ai2[k]));
            }
            int4* own = buf + t * 3;
            own[0] = make_int4(bci(u[0]), bci(u[1]), bci(u[2]), bci(u[3]));
            own[1] = make_int4(bci(v[0]), bci(v[1]), bci(v[2]), bci(v[3]));
            __syncthreads();                        // writes visible
            const int4* par = buf + (t ^ Minv[pb]) * 3;
            const int4 qu = par[0];
            const int4 qv = par[1];
            const int U[4] = {qu.x, qu.y, qu.z, qu.w};
            const int V[4] = {qv.x, qv.y, qv.z, qv.w};
#pragma unroll
            for (int k = 0; k < 4; ++k) {
                const h2 nr = __hsub2(__hfma2(ncsi2, ai2[k], __hmul2(A2, ar2[k])), bch2(U[k]));
                const h2 ni = __hsub2(__hfma2(csi2,  ar2[k], __hmul2(A2, ai2[k])), bch2(V[k]));
                ar2[k] = nr; ai2[k] = ni;
            }
        }
        // ---- wires 3..8: lane bits 5..0, packed bpermute ----
#pragma unroll
        for (int w = 3; w < 9; ++w) {
            const int4 rv = *reinterpret_cast<const int4*>(tbl + base + w);
            const int pb = 8 - w;                   // 5..0
            const bool bs = (p >> pb) & 1;
            const h2 A2    = bch2(rv.x);
            const int bi   = bs ? rv.y : (rv.y ^ NEGMASK);
            const h2 csi2  = bch2(bi);
            const h2 ncsi2 = bch2(bi ^ NEGMASK);
            const h2 cor2  = bch2(bs ? rv.z : (rv.z ^ NEGMASK));
            const h2 D2    = bch2(rv.w);
            const h2 nD2   = bch2(rv.w ^ NEGMASK);
            const int addr4 = ((t & 63) ^ Minv[pb]) << 2;   // Minv[pb] < 64
            h2 u[4], v[4];
#pragma unroll
            for (int k = 0; k < 4; ++k) {
                u[k] = __hfma2(nD2, ai2[k], __hmul2(cor2, ar2[k]));
                v[k] = __hfma2(D2,  ar2[k], __hmul2(cor2, ai2[k]));
            }
            h2 U[4], V[4];
#pragma unroll
            for (int k = 0; k < 4; ++k) {
                U[k] = bperm2(addr4, u[k]);
                V[k] = bperm2(addr4, v[k]);
            }
#pragma unroll
            for (int k = 0; k < 4; ++k) {
                const h2 nr = __hsub2(__hfma2(ncsi2, ai2[k], __hmul2(A2, ar2[k])), U[k]);
                const h2 ni = __hsub2(__hfma2(csi2,  ar2[k], __hmul2(A2, ai2[k])), V[k]);
                ar2[k] = nr; ai2[k] = ni;
            }
        }
        // ---- wires 9..10: reg bits 2..1, aligned-half2 pairs (R7 form) ----
        {
            const int4 rv = *reinterpret_cast<const int4*>(tbl + base + 9);
            H2C C; C.a = bch2(rv.x); C.b = bch2(rv.y); C.c = bch2(rv.z); C.d = bch2(rv.w);
            C.nb = bch2(rv.y ^ NEGMASK); C.nc = bch2(rv.z ^ NEGMASK); C.nd = bch2(rv.w ^ NEGMASK);
            reg_pair(ar2[0], ai2[0], ar2[2], ai2[2], C);    // BIT2: (0,2),(1,3)
            reg_pair(ar2[1], ai2[1], ar2[3], ai2[3], C);
        }
        {
            const int4 rv = *reinterpret_cast<const int4*>(tbl + base + 10);
            H2C C; C.a = bch2(rv.x); C.b = bch2(rv.y); C.c = bch2(rv.z); C.d = bch2(rv.w);
            C.nb = bch2(rv.y ^ NEGMASK); C.nc = bch2(rv.z ^ NEGMASK); C.nd = bch2(rv.w ^ NEGMASK);
            reg_pair(ar2[0], ai2[0], ar2[1], ai2[1], C);    // BIT1: (0,1),(2,3)
            reg_pair(ar2[2], ai2[2], ar2[3], ai2[3], C);
        }
        // ---- wire 11: reg bit 0, intra-half2 (R12-verified constants) ----
        {
            const int4 wv = *reinterpret_cast<const int4*>(w11 + l*4);
            const h2 cP  = bch2(wv.x);
            const h2 cQ  = bch2(wv.y);
            const h2 cR  = bch2(wv.z);
            const h2 cS  = bch2(wv.w);
            const h2 cQn = bch2(wv.y ^ NEGMASK);
            const h2 cSn = bch2(wv.w ^ NEGMASK);
#pragma unroll
            for (int k = 0; k < 4; ++k) {
                const h2 arv = ar2[k], aiv = ai2[k];
                const h2 arx = __low2half2(arv), ary = __high2half2(arv);
                const h2 aix = __low2half2(aiv), aiy = __high2half2(aiv);
                ar2[k] = __hfma2(cS,  aiy, __hfma2(cR, ary, __hfma2(cQ,  aix, __hmul2(cP, arx))));
                ai2[k] = __hfma2(cSn, ary, __hfma2(cR, aiy, __hfma2(cQn, arx, __hmul2(cP, aix))));
            }
        }
        // ---- CNOT chain: reg part physical (packed), thread part deferred --
        const int c = __popc(p) & 1;                // parity of OLD logical p
        {
            h2 t0;                                  // cond swap r ^ 4
            t0 = ar2[0]; ar2[0] = c ? ar2[2] : ar2[0]; ar2[2] = c ? t0 : ar2[2];
            t0 = ar2[1]; ar2[1] = c ? ar2[3] : ar2[1]; ar2[3] = c ? t0 : ar2[3];
            t0 = ai2[0]; ai2[0] = c ? ai2[2] : ai2[0]; ai2[2] = c ? t0 : ai2[2];
            t0 = ai2[1]; ai2[1] = c ? ai2[3] : ai2[1]; ai2[3] = c ? t0 : ai2[3];
            // gray3 relabel: h1 <- swap(h1); h2 <- h3; h3 <- swap(h2_old)
            h2 tmp = ar2[2]; ar2[2] = ar2[3]; ar2[3] = rot16(tmp);
            ar2[1] = rot16(ar2[1]);
            tmp = ai2[2]; ai2[2] = ai2[3]; ai2[3] = rot16(tmp);
            ai2[1] = rot16(ai2[1]);
        }
        p = ginv9(p);
#pragma unroll
        for (int pb = 8; pb >= 1; --pb) Minv[pb] ^= Minv[pb-1];
    }

    // ---- write column in LOGICAL order: y = (p<<3) | j ----
    float4* dst4 = reinterpret_cast<float4*>(cols + b*4096 + (p << 3));
#pragma unroll
    for (int k = 0; k < 4; ++k)
        dst4[k] = make_float4(__low2float(ar2[k]),  __low2float(ai2[k]),
                              __high2float(ar2[k]), __high2float(ai2[k]));
}

// ---- kernel 2: redundant G-reduce per block + per-sample quadratic form ---
__global__ __launch_bounds__(256)
void finish_kernel(const float* __restrict__ sb,
                   const float2* __restrict__ cols,
                   const float* __restrict__ hw,
                   const float* __restrict__ hb,
                   float* __restrict__ out, int B) {
    const int tid  = threadIdx.x;
    const int lane = tid & 63, wid = tid >> 6;

    float hwv[12];
#pragma unroll
    for (int w = 0; w < 12; ++w) hwv[w] = hw[w];

    // K(q) splits: q = (it<<8) | tid -> Klo over wires 4..11 (bits 7..0)
    float Klo = 0.f;
#pragma unroll
    for (int w = 4; w < 12; ++w)
        Klo += ((tid >> (11 - w)) & 1) ? -hwv[w] : hwv[w];

    float g[10];
#pragma unroll
    for (int m = 0; m < 10; ++m) g[m] = 0.f;

#pragma unroll 1
    for (int it = 0; it < 16; ++it) {
        const int q = (it << 8) | tid;
        const float2 c0 = cols[q];
        const float2 c1 = cols[4096  + q];
        const float2 c2 = cols[8192  + q];
        const float2 c3 = cols[12288 + q];
        float K = Klo;
#pragma unroll
        for (int w = 0; w < 4; ++w)                 // wires 0..3: bits 11..8
            K += ((it >> (3 - w)) & 1) ? -hwv[w] : hwv[w];
        g[0] += K * (c0.x*c0.x + c0.y*c0.y);
        g[1] += K * (c1.x*c1.x + c1.y*c1.y);
        g[2] += K * (c2.x*c2.x + c2.y*c2.y);
        g[3] += K * (c3.x*c3.x + c3.y*c3.y);
        g[4] += K * (c0.x*c1.x + c0.y*c1.y);
        g[5] += K * (c2.x*c3.x + c2.y*c3.y);
        g[6] += K * (c0.x*c2.y - c0.y*c2.x);
        g[7] += K * (c0.x*c3.y - c0.y*c3.x);
        g[8] += K * (c1.x*c2.y - c1.y*c2.x);
        g[9] += K * (c1.x*c3.y - c1.y*c3.x);
    }

    // block reduce: wave butterfly then cross-wave via LDS
    __shared__ float gsh[4][10];
#pragma unroll
    for (int m = 0; m < 10; ++m) {
#pragma unroll
        for (int off = 1; off < 64; off <<= 1)
            g[m] += bpermf((lane ^ off) << 2, g[m]);
    }
    if (lane == 0) {
#pragma unroll
        for (int m = 0; m < 10; ++m) gsh[wid][m] = g[m];
    }
    __syncthreads();
    float G[10];
#pragma unroll
    for (int m = 0; m < 10; ++m) {
        const float s = gsh[0][m] + gsh[1][m] + gsh[2][m] + gsh[3][m];
        G[m] = (m < 4) ? s : 2.f * s;               // fold 2*Re / 2*Im factor
    }

    const int i = blockIdx.x * 256 + tid;
    if (i < B) {
        const float2 x = *reinterpret_cast<const float2*>(sb + i*8);
        float c0, s0, c1, s1;
        __sincosf(0.5f * x.x, &s0, &c0);
        __sincosf(0.5f * x.y, &s1, &c1);
        const float a0 = c0*c1, a1 = c0*s1, a2 = s0*c1, a3 = s0*s1;
        const float r = G[0]*a0*a0 + G[1]*a1*a1 + G[2]*a2*a2 + G[3]*a3*a3
                      + G[4]*(a0*a1) + G[5]*(a2*a3)
                      + G[6]*(a0*a2) + G[7]*(a0*a3)
                      + G[8]*(a1*a2) + G[9]*(a1*a3);
        out[i] = r + hb[0];
    }
}

extern "C" void kernel_launch(void* const* d_in, const int* in_sizes, int n_in,
                              void* d_out, int out_size, void* d_ws, size_t ws_size,
                              hipStream_t stream) {
    const float* sb  = (const float*)d_in[0];
    const float* wts = (const float*)d_in[1];
    const float* hw  = (const float*)d_in[2];
    const float* hb  = (const float*)d_in[3];
    float* out = (float*)d_out;
    GateRecH2* tbl = (GateRecH2*)d_ws;                       // 96*16 = 1536 B
    h2* w11 = (h2*)((char*)d_ws + 1536);                     // 8*4 h2 = 128 B
    float2* cols = (float2*)((char*)d_ws + 4096);            // 128 KB, 16B-aligned
    const int B = in_sizes[0] / 8;                           // (B,8) state_batch
    coeff_kernel <<<1, 128, 0, stream>>>(wts, tbl, w11);
    sim_kernel   <<<4, 512, 0, stream>>>(tbl, w11, cols);
    finish_kernel<<<(B + 255)/256, 256, 0, stream>>>(sb, cols, hw, hb, out, B);
}